// Round 8
// baseline (586.769 us; speedup 1.0000x reference)
//
#include <hip/hip_runtime.h>

// Problem constants (match reference)
constexpr int HSd = 192, WSd = 192, HRd = 192, WRd = 192;
constexpr int Cd  = 512;
constexpr int NS  = HSd * WSd;   // 36864 src pixels (< 65536 -> u16 indexable)
constexpr int NR  = HRd * WRd;   // 36864 ref pixels
constexpr int CAP = 64;          // dir2 slots (Poisson lambda~8.7; P(>64)~0)
constexpr float W_SRC = 1.0f / (float)NS;   // ws
constexpr float W_REF = 2.0f / (float)NR;   // wr
constexpr float TAUc   = 0.05f;
constexpr float ALPHAc = 0.8f;

// prep roles
constexpr int RSB = 576;   // response blocks (64 px each)
constexpr int D1B = NS / 256;  // 144 dir1-build blocks
constexpr int D2B = NR / 256;  // 144 dir2-build blocks

// ---------------------------------------------------------------------------
// prep2: role-split. [0,RSB): response + minmax. [RSB,RSB+D1B): dir1 u16 SoA
// tap planes (sentinel 0xFFFF). [RSB+D1B,..): dir2 u16 slot-major lists.
__global__ __launch_bounds__(256)
void prep2(const float* __restrict__ f_a, const int* __restrict__ nnf_sr,
           const int* __restrict__ nnf_rs,
           unsigned short* __restrict__ idx1, unsigned short* __restrict__ list2,
           unsigned int* __restrict__ cnt, float* __restrict__ resp,
           unsigned int* __restrict__ minmax) {
    __shared__ __align__(16) float4 part[16 * 16];
    const int b = blockIdx.x;
    const int t = threadIdx.x;

    if (b < RSB) {
        // ---- response: 64 px/block; 16 channel-groups x 16 float4-pixels ----
        const int px4 = t & 15;          // float4 pixel within block
        const int cg  = t >> 4;          // channel group (32 ch each)
        const int b4  = b * 16;          // block base in float4 units
        const float4* f4 = (const float4*)f_a;
        float4 a = make_float4(0.f, 0.f, 0.f, 0.f);
#pragma unroll
        for (int cc = 0; cc < 32; ++cc) {
            const float4 v = f4[(size_t)(cg * 32 + cc) * (NS / 4) + b4 + px4];
            a.x = fmaf(v.x, v.x, a.x);
            a.y = fmaf(v.y, v.y, a.y);
            a.z = fmaf(v.z, v.z, a.z);
            a.w = fmaf(v.w, v.w, a.w);
        }
        part[px4 * 16 + cg] = a;
        __syncthreads();
        if (t < 16) {
            float4 tot = make_float4(0.f, 0.f, 0.f, 0.f);
#pragma unroll
            for (int cg2 = 0; cg2 < 16; ++cg2) {
                const float4 s = part[t * 16 + cg2];
                tot.x += s.x; tot.y += s.y; tot.z += s.z; tot.w += s.w;
            }
            ((float4*)resp)[b4 + t] = tot;
            float mn = fminf(fminf(tot.x, tot.y), fminf(tot.z, tot.w));
            float mx = fmaxf(fmaxf(tot.x, tot.y), fmaxf(tot.z, tot.w));
#pragma unroll
            for (int off = 8; off; off >>= 1) {   // lanes 0..15 butterfly
                mn = fminf(mn, __shfl_xor(mn, off, 64));
                mx = fmaxf(mx, __shfl_xor(mx, off, 64));
            }
            if (t == 0) {
                atomicMin(&minmax[0], __float_as_uint(mn));
                atomicMax(&minmax[1], __float_as_uint(mx));
            }
        }
    } else if (b < RSB + D1B) {
        // ---- dir1 build: per target, 9 tap source indices (or sentinel) ----
        const int tt = (b - RSB) * 256 + t;
        const int ty = tt / WSd, tx = tt % WSd;
#pragma unroll
        for (int j = 0; j < 9; ++j) {
            const int dy = j / 3 - 1, dx = j % 3 - 1;
            const int sy = ty - dy, sx = tx - dx;
            unsigned short v = 0xFFFFu;
            if (sy >= 0 && sy < HSd && sx >= 0 && sx < WSd) {
                const int s = sy * WSd + sx;
                const int gy = nnf_sr[2 * s] + dy;
                const int gx = nnf_sr[2 * s + 1] + dx;
                if (gy >= 0 && gy < HRd && gx >= 0 && gx < WRd)
                    v = (unsigned short)(gy * WRd + gx);
            }
            idx1[(size_t)j * NS + tt] = v;
        }
    } else {
        // ---- dir2 build: index-only scatter into slot-major u16 lists ----
        const int r = (b - RSB - D1B) * 256 + t;
        const int ry = r / WRd, rx = r % WRd;
        const int ty0 = nnf_rs[2 * r], tx0 = nnf_rs[2 * r + 1];
#pragma unroll
        for (int dy = -1; dy <= 1; ++dy) {
#pragma unroll
            for (int dx = -1; dx <= 1; ++dx) {
                const int ty = ty0 + dy, tx = tx0 + dx;
                const int gy = ry + dy,  gx = rx + dx;
                if (ty >= 0 && ty < HSd && tx >= 0 && tx < WSd &&
                    gy >= 0 && gy < HRd && gx >= 0 && gx < WRd) {
                    const int tt = ty * WSd + tx;
                    const unsigned int pos = atomicAdd(&cnt[tt], 1u);
                    if (pos < CAP)
                        list2[(size_t)pos * NS + tt] = (unsigned short)(gy * WRd + gx);
                }
            }
        }
    }
}

// ---------------------------------------------------------------------------
// gather_lds: one block per channel. Whole 192x192 fp32 ref plane in LDS
// (144 KiB). All vote contributions become LDS reads; ref is read from HBM
// exactly once, coalesced. Blend fused into the target loop.
__global__ __launch_bounds__(1024)
void gather_lds(const float* __restrict__ ref, const float* __restrict__ f_a,
                const unsigned short* __restrict__ idx1,
                const unsigned short* __restrict__ list2,
                const unsigned int* __restrict__ cnt,
                const float* __restrict__ resp,
                const unsigned int* __restrict__ minmax,
                float* __restrict__ out) {
    __shared__ float plane[NR];   // 147456 B
    const int c = blockIdx.x;
    const int tid = threadIdx.x;
    const size_t cbase = (size_t)c * NS;

    // stage the channel plane (9 float4 per thread, fully coalesced)
    const float4* rp = (const float4*)(ref + (size_t)c * NR);
    float4* pl4 = (float4*)plane;
#pragma unroll
    for (int i = 0; i < NR / 4 / 1024; ++i)
        pl4[tid + 1024 * i] = rp[tid + 1024 * i];
    __syncthreads();

    const float mn = __uint_as_float(minmax[0]);
    const float mx = __uint_as_float(minmax[1]);
    const float inv_range = 1.f / (mx - mn);

    for (int t = tid; t < NS; t += 1024) {
        float a1 = 0.f;
        int n1 = 0;
#pragma unroll
        for (int j = 0; j < 9; ++j) {
            const unsigned short gi = idx1[(size_t)j * NS + t];
            if (gi != 0xFFFFu) { a1 += plane[gi]; ++n1; }
        }
        const int n2 = min((int)cnt[t], CAP);
        float a2 = 0.f;
        for (int j = 0; j < n2; ++j)
            a2 += plane[list2[(size_t)j * NS + t]];

        const float wsum = (float)n1 * W_SRC + (float)n2 * W_REF;
        const float inv = (wsum == 0.f) ? 0.f : 1.f / wsum;  // weight==0 -> guide 0
        const float guide = (a1 * W_SRC + a2 * W_REF) * inv;

        const float rn = (resp[t] - mn) * inv_range;
        const float w = (rn > TAUc) ? ALPHAc : 0.f;
        out[cbase + t] = f_a[cbase + t] * w + guide * (1.f - w);
    }
}

// ---------------------------------------------------------------------------
extern "C" void kernel_launch(void* const* d_in, const int* in_sizes, int n_in,
                              void* d_out, int out_size, void* d_ws, size_t ws_size,
                              hipStream_t stream) {
    const float* ref    = (const float*)d_in[0];
    const float* f_a    = (const float*)d_in[1];
    const int*   nnf_sr = (const int*)d_in[2];
    const int*   nnf_rs = (const int*)d_in[3];
    float* out = (float*)d_out;

    char* ws = (char*)d_ws;
    size_t off = 0;
    unsigned short* list2 = (unsigned short*)(ws + off); off += (size_t)CAP * NS * 2;  // 4.7 MB
    unsigned short* idx1  = (unsigned short*)(ws + off); off += (size_t)9 * NS * 2;    // 664 KB
    unsigned int*   cnt   = (unsigned int*)(ws + off);   off += (size_t)NS * 4;
    float*          resp  = (float*)(ws + off);          off += (size_t)NS * 4;
    unsigned int*   minmax = (unsigned int*)(ws + off);  off += 16;

    // cnt = 0; minmax[0](min) = 0xFFFFFFFF (uint upper bound, resp >= 0);
    // minmax[1](max) = 0
    hipMemsetAsync(cnt, 0, (size_t)NS * 4, stream);
    hipMemsetAsync(minmax, 0xFF, 4, stream);
    hipMemsetAsync(minmax + 1, 0, 4, stream);

    prep2<<<RSB + D1B + D2B, 256, 0, stream>>>(f_a, nnf_sr, nnf_rs,
                                               idx1, list2, cnt, resp, minmax);
    gather_lds<<<Cd, 1024, 0, stream>>>(ref, f_a, idx1, list2, cnt, resp,
                                        minmax, out);
}

// Round 9
// 334.672 us; speedup vs baseline: 1.7533x; 1.7533x over previous
//
#include <hip/hip_runtime.h>

// Problem constants (match reference)
constexpr int HSd = 192, WSd = 192, HRd = 192, WRd = 192;
constexpr int Cd  = 512;
constexpr int NS  = HSd * WSd;   // 36864 src pixels
constexpr int NR  = HRd * WRd;   // 36864 ref pixels
constexpr int CAP = 64;          // per-target dir2 list capacity (Poisson lambda~8.7)
constexpr float W_SRC = 1.0f / (float)NS;   // ws
constexpr float W_REF = 2.0f / (float)NR;   // wr
constexpr float TAUc   = 0.05f;
constexpr float ALPHAc = 0.8f;

constexpr int TT  = 16;            // targets per block (gather)
constexpr int LPT = 16;            // lanes per target
constexpr int LDS_STRIDE = 516;    // words; 16B-aligned rows, mild conflicts (measured negligible)

// prep kernel block-role split
constexpr int TRB = (NR / 64) * (Cd / 64);  // 4608 transpose blocks
constexpr int RSB = 144;                    // response blocks (256 px each)
constexpr int BLB = 144;                    // build_list blocks (256 ref px each)

// fp32 -> bf16 round-to-nearest-even (bit trick; inputs are finite randn)
__device__ __forceinline__ unsigned short f2bf(float f) {
    const unsigned u = __float_as_uint(f);
    return (unsigned short)((u + 0x7FFFu + ((u >> 16) & 1u)) >> 16);
}
__device__ __forceinline__ float bflo(unsigned u) { return __uint_as_float(u << 16); }
__device__ __forceinline__ float bfhi(unsigned u) { return __uint_as_float(u & 0xFFFF0000u); }

// ---------------------------------------------------------------------------
// Fused prep: [0,TRB) transpose ref -> bf16 ref_t; [TRB,TRB+RSB) response +
// min/max; rest build dir2 lists. Identical structure to round 7 except the
// transpose write side converts to bf16 (write volume halved).
__global__ __launch_bounds__(256)
void prep_kernel(const float* __restrict__ ref, const float* __restrict__ f_a,
                 const int* __restrict__ nnf_rs,
                 unsigned short* __restrict__ ref_t, int* __restrict__ cnt,
                 int* __restrict__ list, float* __restrict__ resp,
                 unsigned int* __restrict__ minmax) {
    __shared__ __align__(16) float smem[64 * 65];   // 16.6 KB
    const int b = blockIdx.x;
    const int t = threadIdx.x;

    if (b < TRB) {
        // ---- transpose role: 64px x 64ch tile; float4 read, bf16x4 write ----
        const int pt = b % (NR / 64), ct = b / (NR / 64);
        const int p0 = pt * 64, c0 = ct * 64;
        const int fc = t & 15;        // float4 / bf16x4 column
        const int r4 = t >> 4;        // 0..15
        const float4* rf4 = (const float4*)ref;
#pragma unroll
        for (int k = 0; k < 4; ++k) {
            const int row = r4 + 16 * k;                       // channel within tile
            const float4 v = rf4[((size_t)(c0 + row) * NR + p0) / 4 + fc];
            smem[row * 65 + 4 * fc + 0] = v.x;
            smem[row * 65 + 4 * fc + 1] = v.y;
            smem[row * 65 + 4 * fc + 2] = v.z;
            smem[row * 65 + 4 * fc + 3] = v.w;
        }
        __syncthreads();
#pragma unroll
        for (int k = 0; k < 4; ++k) {
            const int p = r4 + 16 * k;                         // pixel within tile
            ushort4 h;
            h.x = f2bf(smem[(4 * fc + 0) * 65 + p]);
            h.y = f2bf(smem[(4 * fc + 1) * 65 + p]);
            h.z = f2bf(smem[(4 * fc + 2) * 65 + p]);
            h.w = f2bf(smem[(4 * fc + 3) * 65 + p]);
            *reinterpret_cast<ushort4*>(ref_t + (size_t)(p0 + p) * Cd + c0 + 4 * fc) = h;
        }
    } else if (b < TRB + RSB) {
        // ---- response role: 256 px/block, block-level min/max reduce ----
        const int rb = b - TRB;
        const int lane = t & 63;      // float4 pixel within block
        const int q = t >> 6;         // channel quarter
        const int base4 = rb * 64;
        const float4* f4 = (const float4*)f_a;
        float4 a = make_float4(0.f, 0.f, 0.f, 0.f);
        for (int cc = 0; cc < Cd / 4; ++cc) {
            const int c = q * (Cd / 4) + cc;
            const float4 v = f4[(size_t)c * (NS / 4) + base4 + lane];
            a.x = fmaf(v.x, v.x, a.x);
            a.y = fmaf(v.y, v.y, a.y);
            a.z = fmaf(v.z, v.z, a.z);
            a.w = fmaf(v.w, v.w, a.w);
        }
        float4* part = (float4*)smem;
        part[q * 64 + lane] = a;
        __syncthreads();
        if (q == 0) {                 // one full wave
            const float4 s0 = part[lane], s1 = part[64 + lane];
            const float4 s2 = part[128 + lane], s3 = part[192 + lane];
            float4 tot;
            tot.x = s0.x + s1.x + s2.x + s3.x;
            tot.y = s0.y + s1.y + s2.y + s3.y;
            tot.z = s0.z + s1.z + s2.z + s3.z;
            tot.w = s0.w + s1.w + s2.w + s3.w;
            ((float4*)resp)[base4 + lane] = tot;
            float mn = fminf(fminf(tot.x, tot.y), fminf(tot.z, tot.w));
            float mx = fmaxf(fmaxf(tot.x, tot.y), fmaxf(tot.z, tot.w));
#pragma unroll
            for (int off = 32; off; off >>= 1) {
                mn = fminf(mn, __shfl_xor(mn, off, 64));
                mx = fmaxf(mx, __shfl_xor(mx, off, 64));
            }
            if (lane == 0) {
                atomicMin(&minmax[0], __float_as_uint(mn));
                atomicMax(&minmax[1], __float_as_uint(mx));
            }
        }
    } else {
        // ---- build_list role: dir2 (ref->src) index-only scatter ----
        const int r = (b - TRB - RSB) * 256 + t;
        const int ry = r / WRd, rx = r % WRd;
        const int ty0 = nnf_rs[2 * r], tx0 = nnf_rs[2 * r + 1];
#pragma unroll
        for (int dy = -1; dy <= 1; ++dy) {
#pragma unroll
            for (int dx = -1; dx <= 1; ++dx) {
                const int ty = ty0 + dy, tx = tx0 + dx;
                const int gy = ry + dy,  gx = rx + dx;
                if (ty >= 0 && ty < HSd && tx >= 0 && tx < WSd &&
                    gy >= 0 && gy < HRd && gx >= 0 && gx < WRd) {
                    const int tt = ty * WSd + tx;
                    const int pos = atomicAdd(&cnt[tt], 1);
                    if (pos < CAP) list[tt * CAP + pos] = gy * WRd + gx;
                }
            }
        }
    }
}

// accumulate one bf16 pixel-row fragment (lane's 32 channels) with weight w
__device__ __forceinline__ void accum_row(const uint4* __restrict__ rt,
                                          size_t gbase, int l, float w,
                                          float (&acc)[4][8]) {
#pragma unroll
    for (int m = 0; m < 4; ++m) {
        const uint4 v = rt[gbase + l + 16 * m];
        acc[m][0] = fmaf(bflo(v.x), w, acc[m][0]);
        acc[m][1] = fmaf(bfhi(v.x), w, acc[m][1]);
        acc[m][2] = fmaf(bflo(v.y), w, acc[m][2]);
        acc[m][3] = fmaf(bfhi(v.y), w, acc[m][3]);
        acc[m][4] = fmaf(bflo(v.z), w, acc[m][4]);
        acc[m][5] = fmaf(bfhi(v.z), w, acc[m][5]);
        acc[m][6] = fmaf(bflo(v.w), w, acc[m][6]);
        acc[m][7] = fmaf(bfhi(v.w), w, acc[m][7]);
    }
}

// ---------------------------------------------------------------------------
// Fused vote-gather on bf16 ref_t (+ normalize + LDS transpose + blend +
// channel-major write). Structure identical to round 7; fragment loads are
// 4x uint4 (8 bf16 each) per contribution per lane -> half the fetch bytes.
__global__ __launch_bounds__(256)
void gather_fused(const unsigned short* __restrict__ ref_t,
                  const int* __restrict__ nnf_sr,
                  const int* __restrict__ cnt, const int* __restrict__ list,
                  const float* __restrict__ f_a, const float* __restrict__ resp,
                  const unsigned int* __restrict__ minmax,
                  float* __restrict__ out) {
    __shared__ float lds[TT][LDS_STRIDE];
    const int tid = threadIdx.x;
    const int k = tid >> 4;          // target within tile (gather phase)
    const int l = tid & 15;          // lane within target -> channel group
    const int t0 = blockIdx.x * TT;
    const int t = t0 + k;
    const int ty = t / WSd, tx = t % WSd;

    const uint4* rt = (const uint4*)ref_t;   // 64 uint4 per pixel row (1 KB)
    float acc[4][8];
#pragma unroll
    for (int m = 0; m < 4; ++m)
#pragma unroll
        for (int e = 0; e < 8; ++e) acc[m][e] = 0.f;
    int n1 = 0;

    // dir1 (src->ref): pure 9-tap gather, inverted from the reference scatter
#pragma unroll
    for (int dy = -1; dy <= 1; ++dy) {
#pragma unroll
        for (int dx = -1; dx <= 1; ++dx) {
            const int sy = ty - dy, sx = tx - dx;
            if (sy >= 0 && sy < HSd && sx >= 0 && sx < WSd) {
                const int s = sy * WSd + sx;
                const int gy = nnf_sr[2 * s] + dy;
                const int gx = nnf_sr[2 * s + 1] + dx;
                if (gy >= 0 && gy < HRd && gx >= 0 && gx < WRd) {
                    accum_row(rt, (size_t)(gy * WRd + gx) * 64, l, W_SRC, acc);
                    ++n1;
                }
            }
        }
    }

    // dir2 (ref->src): precomputed per-target index list
    const int n2 = min(cnt[t], CAP);
    for (int j = 0; j < n2; ++j)
        accum_row(rt, (size_t)list[t * CAP + j] * 64, l, W_REF, acc);

    const float wsum = (float)n1 * W_SRC + (float)n2 * W_REF;
    const float inv = (wsum == 0.f) ? 0.f : 1.f / wsum;  // weight==0 -> guide 0

    // stage normalized guide into LDS (pixel-major)
#pragma unroll
    for (int m = 0; m < 4; ++m) {
        float4 g0, g1;
        g0.x = acc[m][0] * inv;  g0.y = acc[m][1] * inv;
        g0.z = acc[m][2] * inv;  g0.w = acc[m][3] * inv;
        g1.x = acc[m][4] * inv;  g1.y = acc[m][5] * inv;
        g1.z = acc[m][6] * inv;  g1.w = acc[m][7] * inv;
        float* dst = &lds[k][8 * (l + 16 * m)];
        ((float4*)dst)[0] = g0;
        ((float4*)dst)[1] = g1;
    }
    __syncthreads();

    // transpose-read + blend + channel-major coalesced write (64B segments)
    const float mn = __uint_as_float(minmax[0]);
    const float mx = __uint_as_float(minmax[1]);
    const float inv_range = 1.f / (mx - mn);
    const int tt = tid & 15;   // target within tile (write phase)
    const int c0 = tid >> 4;   // 0..15
    const float rn = (resp[t0 + tt] - mn) * inv_range;
    const float w = (rn > TAUc) ? ALPHAc : 0.f;
    const float omw = 1.f - w;
#pragma unroll
    for (int m = 0; m < 32; ++m) {
        const int c = c0 + 16 * m;
        const float g = lds[tt][c];
        const size_t idx = (size_t)c * NS + t0 + tt;
        out[idx] = f_a[idx] * w + g * omw;
    }
}

// ---------------------------------------------------------------------------
extern "C" void kernel_launch(void* const* d_in, const int* in_sizes, int n_in,
                              void* d_out, int out_size, void* d_ws, size_t ws_size,
                              hipStream_t stream) {
    const float* ref    = (const float*)d_in[0];
    const float* f_a    = (const float*)d_in[1];
    const int*   nnf_sr = (const int*)d_in[2];
    const int*   nnf_rs = (const int*)d_in[3];
    float* out = (float*)d_out;

    char* ws = (char*)d_ws;
    size_t off = 0;
    unsigned short* ref_t = (unsigned short*)(ws + off); off += (size_t)NR * Cd * 2;  // 37.7 MB
    int*   list  = (int*)(ws + off);         off += (size_t)NS * CAP * sizeof(int);   // 9.4 MB
    int*   cnt   = (int*)(ws + off);         off += (size_t)NS * sizeof(int);
    float* resp  = (float*)(ws + off);       off += (size_t)NS * sizeof(float);
    unsigned int* minmax = (unsigned int*)(ws + off); off += 16;

    // cnt = 0; minmax[0](min) = 0xFFFFFFFF (uint upper bound, resp >= 0);
    // minmax[1](max) = 0
    hipMemsetAsync(cnt, 0, (size_t)NS * sizeof(int), stream);
    hipMemsetAsync(minmax, 0xFF, 4, stream);
    hipMemsetAsync(minmax + 1, 0, 4, stream);

    prep_kernel<<<TRB + RSB + BLB, 256, 0, stream>>>(ref, f_a, nnf_rs,
                                                     ref_t, cnt, list, resp, minmax);
    gather_fused<<<NS / TT, 256, 0, stream>>>(ref_t, nnf_sr, cnt, list,
                                              f_a, resp, minmax, out);
}